// Round 10
// baseline (869.509 us; speedup 1.0000x reference)
//
#include <hip/hip_runtime.h>

// ---------------- types / helpers ----------------
typedef unsigned short u16;
typedef __bf16 bf16x8 __attribute__((ext_vector_type(8)));
typedef float floatx4 __attribute__((ext_vector_type(4)));

#define DIM 512
#define HEADS 8
#define DH 64
#define SEQ 4096
#define BATCH 2
#define ROWS (BATCH * SEQ) /* 8192 */
#define FFDIM 2048
#define QKVW 1536 /* fused qkv row width */
#define LSTRIDE 3145728L /* repacked weight elems per layer */
#define GK 512   /* K of all gemm8 GEMMs (QKV, W1) */

#define SBAR0() __builtin_amdgcn_sched_barrier(0)
#define ASM_VMCNT(n) asm volatile("s_waitcnt vmcnt(" #n ")" ::: "memory")

__device__ __forceinline__ float b2f(u16 u) {
  union { float f; unsigned int i; } c; c.i = ((unsigned int)u) << 16; return c.f;
}
__device__ __forceinline__ u16 f2b(float f) {
  union { float f; unsigned int i; } c; c.f = f;
  unsigned int r = c.i + 0x7FFFu + ((c.i >> 16) & 1u);
  return (u16)(r >> 16);
}
__device__ __forceinline__ float ldin(const void* p, long i, int bf) {
  return bf ? b2f(((const u16*)p)[i]) : ((const float*)p)[i];
}
// async global->LDS, 16 bytes/lane. LDS dest = base + lane*16 (HW); global addr per-lane.
__device__ __forceinline__ void ld16(const u16* g, u16* l) {
  __builtin_amdgcn_global_load_lds((const __attribute__((address_space(1))) void*)g,
                                   (__attribute__((address_space(3))) void*)l, 16, 0, 0);
}
// unpack 8 u16 (as uint4) -> 8 floats
__device__ __forceinline__ void unpk8(uint4 p, float* o) {
  o[0] = b2f((u16)(p.x & 0xFFFF)); o[1] = b2f((u16)(p.x >> 16));
  o[2] = b2f((u16)(p.y & 0xFFFF)); o[3] = b2f((u16)(p.y >> 16));
  o[4] = b2f((u16)(p.z & 0xFFFF)); o[5] = b2f((u16)(p.z >> 16));
  o[6] = b2f((u16)(p.w & 0xFFFF)); o[7] = b2f((u16)(p.w >> 16));
}
// exact-enough GELU: erf via Abramowitz-Stegun 7.1.26 (|err| <= 1.5e-7) + fast exp.
__device__ __forceinline__ float fast_gelu(float v) {
  float z = fabsf(v) * 0.70710678118654752f;
  float t = 1.0f / (1.0f + 0.3275911f * z);
  float p = t * (0.254829592f +
           t * (-0.284496736f +
           t * (1.421413741f +
           t * (-1.453152027f +
           t * 1.061405429f))));
  float e = __expf(-z * z);
  float er = 1.0f - p * e;             // erf(|z|)
  float s = copysignf(er, v);          // erf(z)
  return 0.5f * v * (1.0f + s);
}

// ---------------- dtype detection ----------------
__global__ void k_detect(const void* __restrict__ g, int* __restrict__ flag) {
  *flag = (((const u16*)g)[0] == 0x3F80u) ? 1 : 0;
}

// ---------------- input x -> f32 / f32 -> out ----------------
__global__ __launch_bounds__(256) void k_x2f(const void* __restrict__ in, float* __restrict__ out,
                                             int n, const int* __restrict__ dt) {
  int bf = *dt;
  int i = blockIdx.x * 256 + threadIdx.x;
  if (i < n) out[i] = ldin(in, i, bf);
}
__global__ __launch_bounds__(256) void k_store(const float* __restrict__ in, void* __restrict__ out,
                                               int n, const int* __restrict__ dt) {
  int bf = *dt;
  int i = blockIdx.x * 256 + threadIdx.x;
  if (i < n) {
    if (bf) ((u16*)out)[i] = f2b(in[i]);
    else ((float*)out)[i] = in[i];
  }
}

// ---------------- weight repack (LDS-tiled, coalesced, batched) ----------------
__device__ __forceinline__ void repack_tile(const void* W, long w_off, u16* R, int N,
                                            int n16tot, int j_off, int kb, int jb, int bf) {
  int t = threadIdx.x;
  __shared__ float tile[32][65];
  int r0 = t >> 6;
  int c = t & 63;
#pragma unroll
  for (int i = 0; i < 8; ++i) {
    int rr = i * 4 + r0;
    tile[rr][c] = ldin(W, w_off + (long)(kb * 32 + rr) * N + jb * 64 + c, bf);
  }
  __syncthreads();
  int lane = t & 63, w = t >> 6;
  alignas(16) u16 tmp[8];
#pragma unroll
  for (int r = 0; r < 8; ++r) tmp[r] = f2b(tile[(lane >> 4) * 8 + r][w * 16 + (lane & 15)]);
  long oidx = (((long)kb * n16tot + j_off + jb * 4 + w) * 64 + lane) * 8;
  *(uint4*)(R + oidx) = *(const uint4*)tmp;
}
// all 512x512 weights: grid (16,8,16); z = layer*4 + type(0=q,1=k,2=v,3=o)
__global__ __launch_bounds__(256) void k_repackQ(const void* wq, const void* wk,
                                                 const void* wv, const void* wo,
                                                 u16* WR, const int* __restrict__ dt) {
  int bf = *dt;
  int z = blockIdx.z, layer = z >> 2, type = z & 3;
  const void* W = (type == 0) ? wq : (type == 1) ? wk : (type == 2) ? wv : wo;
  u16* R = WR + (long)layer * LSTRIDE + (type < 3 ? 0 : 786432);
  int n16tot = (type < 3) ? 96 : 32;
  int j_off = (type < 3) ? type * 32 : 0;
  repack_tile(W, (long)layer * 262144, R, 512, n16tot, j_off, blockIdx.x, blockIdx.y, bf);
}
// w1: grid (16,32,4)
__global__ __launch_bounds__(256) void k_repackF1(const void* w1, u16* WR, const int* __restrict__ dt) {
  int bf = *dt;
  repack_tile(w1, (long)blockIdx.z * 1048576, WR + (long)blockIdx.z * LSTRIDE + 1048576,
              2048, 128, 0, blockIdx.x, blockIdx.y, bf);
}
// w2: grid (64,8,4)
__global__ __launch_bounds__(256) void k_repackF2(const void* w2, u16* WR, const int* __restrict__ dt) {
  int bf = *dt;
  repack_tile(w2, (long)blockIdx.z * 1048576, WR + (long)blockIdx.z * LSTRIDE + 2097152,
              512, 32, 0, blockIdx.x, blockIdx.y, bf);
}

// ---------------- layernorm (f32 in, bf16 out) ----------------
__global__ __launch_bounds__(256) void k_ln(const float* __restrict__ x,
                                            const void* __restrict__ g, const void* __restrict__ b,
                                            long gb_off, u16* __restrict__ out,
                                            const int* __restrict__ dt) {
  int bf = *dt;
  int row = blockIdx.x;
  int t = threadIdx.x;
  const float* xr = x + (size_t)row * DIM;
  float v0 = xr[t], v1 = xr[t + 256];
  float s = v0 + v1;
  float s2 = v0 * v0 + v1 * v1;
#pragma unroll
  for (int off = 32; off > 0; off >>= 1) {
    s += __shfl_down(s, off);
    s2 += __shfl_down(s2, off);
  }
  __shared__ float red[8];
  int lane = t & 63, w = t >> 6;
  if (lane == 0) { red[w] = s; red[4 + w] = s2; }
  __syncthreads();
  float ts = red[0] + red[1] + red[2] + red[3];
  float ts2 = red[4] + red[5] + red[6] + red[7];
  float mean = ts * (1.0f / DIM);
  float var = ts2 * (1.0f / DIM) - mean * mean;
  float rstd = rsqrtf(var + 1e-5f);
  u16* orow = out + (size_t)row * DIM;
  orow[t] = f2b((v0 - mean) * rstd * ldin(g, gb_off + t, bf) + ldin(b, gb_off + t, bf));
  orow[t + 256] = f2b((v1 - mean) * rstd * ldin(g, gb_off + t + 256, bf) + ldin(b, gb_off + t + 256, bf));
}

// ---------------- MFMA GEMM v8 (N=512 GEMMs: WO K=512, W2 K=2048) ----------------
// Round-9 lesson: 128x128/4-wave at grid 256 = 1 wave/SIMD -> no overlap partner ->
// regression. v8 keeps the 0.5 reads/MFMA ratio WITHOUT losing residency:
// 128x64 tile, TWO waves (128 thr), each wave owns 64 rows x all 64 cols
// (afr 4 + bfr 4 = 8 ds_read_b128 per 16 MFMA per kk). Grid (64,8) = 512 blocks,
// LDS 48KB -> 2-3 blocks/CU = 4-6 waves/CU (overlap restored). Free-run sync,
// coalesced swizzled A-staging, single-shot f32 epilogue. unroll 2 (I-cache).
template <int TK>
__global__ __launch_bounds__(128) void k_gemm2w(const u16* __restrict__ A, const u16* __restrict__ BR,
                                                const void* bias, long bias_off,
                                                const float* __restrict__ res, float* __restrict__ outp,
                                                const int* __restrict__ dtflag) {
  constexpr int NKT = TK >> 6;
  constexpr int N16 = 32;  // 512 >> 4
  int lane = threadIdx.x & 63;
  int wid = threadIdx.x >> 6;  // wave 0..1 (64-row halves)
  int m0 = blockIdx.x * 128;
  int n0 = blockIdx.y * 64;
  int n016 = blockIdx.y * 4;

  // 2 bufs x (A 16KB | B 8KB) = 48KB; epilogue reuses 32KB (2 waves x 16KB f32)
  __shared__ alignas(16) u16 smem[24576];

  floatx4 acc[4][4];
#pragma unroll
  for (int mi = 0; mi < 4; ++mi)
#pragma unroll
    for (int j = 0; j < 4; ++j)
#pragma unroll
      for (int r = 0; r < 4; ++r) acc[mi][j][r] = 0.0f;

  // A staging: coalesced 8-row x 128B insts, pre-swizzled source (rule #21 pattern)
  int arow = lane >> 3;
  int acu = ((lane & 7) ^ arow) * 8;
  const u16* AgS = A + (size_t)(m0 + wid * 64 + arow) * TK + acu;

  auto stage = [&](int kb, int b) {
    u16* aL = smem + b * 12288;
    u16* bL = aL + 8192;
#pragma unroll
    for (int j = 0; j < 8; ++j)   // A: 16 row-groups of 8; wave owns wid*8..+7
      ld16(AgS + (size_t)(j * 8) * TK + (size_t)kb * 64, aL + (wid * 8 + j) * 512);
#pragma unroll
    for (int bi = 0; bi < 4; ++bi) { // B: 8 (kk,cg) blocks; g = wid*4+bi
      int g = wid * 4 + bi;
      int kk = g >> 2, cg = g & 3;
      ld16(BR + (((size_t)(kb * 2 + kk) * N16 + n016 + cg) * 64 + lane) * 8,
           bL + g * 512);
    }
  };

  // swizzled A-read offsets (u16)
  int aoff = (lane & 15) * 64;
  int axor = (lane & 7) << 3;
  int ak0 = ((lane >> 4) * 8) ^ axor;
  int ak1 = (32 + (lane >> 4) * 8) ^ axor;

  // prologue: tiles 0 and 1 staged (12 loads each); tile 0 must land
  stage(0, 0);
  stage(1, 1);
  ASM_VMCNT(12);
  __builtin_amdgcn_s_barrier();
  SBAR0();

#pragma unroll 2
  for (int kb = 0; kb < NKT; ++kb) {
    const u16* aL = smem + (kb & 1) * 12288;
    const u16* bL = aL + 8192;
#pragma unroll
    for (int h = 0; h < 2; ++h) {
      int akh = h ? ak1 : ak0;
      bf16x8 afr[4], bfr[4];
#pragma unroll
      for (int mi = 0; mi < 4; ++mi)
        afr[mi] = *(const bf16x8*)(aL + (wid * 4 + mi) * 1024 + aoff + akh);
#pragma unroll
      for (int j = 0; j < 4; ++j)
        bfr[j] = *(const bf16x8*)(bL + ((h * 4 + j) * 64 + lane) * 8);
      __builtin_amdgcn_s_setprio(1);
#pragma unroll
      for (int mi = 0; mi < 4; ++mi)
#pragma unroll
        for (int j = 0; j < 4; ++j)
          acc[mi][j] = __builtin_amdgcn_mfma_f32_16x16x32_bf16(afr[mi], bfr[j], acc[mi][j], 0, 0, 0);
      __builtin_amdgcn_s_setprio(0);
    }
    SBAR0();
    __builtin_amdgcn_s_barrier();        // A: all waves done reading live buf
    if (kb + 2 < NKT) {
      stage(kb + 2, kb & 1);
      ASM_VMCNT(12);                     // tile kb+1 landed; kb+2 in flight
    } else if (kb + 1 < NKT) {
      ASM_VMCNT(0);
    }
    __builtin_amdgcn_s_barrier();        // B: landing is cross-wave
    SBAR0();
  }

  // ---- epilogue: single-shot f32 staging [64][64]/wave, block-XOR swizzle ----
  // write: s=(row>>2)&3; phys col = logical ^ (s<<4) -> 2-way banks on write,
  // even distribution on read (row = p*4 + (l>>4), s uniform per pass).
  float* epf = (float*)smem + wid * 4096;
  int dtv = *dtflag;
  int mWb = m0 + wid * 64;
  float bv[4];
#pragma unroll
  for (int j = 0; j < 4; ++j)
    bv[j] = ldin(bias, bias_off + n0 + j * 16 + (lane & 15), dtv);
#pragma unroll
  for (int mi = 0; mi < 4; ++mi)
#pragma unroll
    for (int j = 0; j < 4; ++j)
#pragma unroll
      for (int r = 0; r < 4; ++r) {
        int row = mi * 16 + (lane >> 4) * 4 + r;
        int s = (row >> 2) & 3;
        int col = (j * 16 + (lane & 15)) ^ (s << 4);
        epf[row * 64 + col] = acc[mi][j][r] + bv[j];
      }
  asm volatile("s_waitcnt lgkmcnt(0)" ::: "memory");
#pragma unroll
  for (int p = 0; p < 16; ++p) {
    int row = p * 4 + (lane >> 4);
    int s = (row >> 2) & 3;
    int col = ((lane & 15) * 4) ^ (s << 4);
    float4 v = *(const float4*)(epf + row * 64 + col);
    size_t gi = (size_t)(mWb + row) * DIM + n0 + (lane & 15) * 4;
    float4 rv = *(const float4*)&res[gi];
    v.x += rv.x; v.y += rv.y; v.z += rv.z; v.w += rv.w;
    *(float4*)&outp[gi] = v;
  }
}

// ---------------- MFMA GEMM v6: 256x256 free-run pipeline (QKV, W1), K=512 ----------
// (round-8 proven configuration, reverted from round-9's NFRAG experiment)
template <bool HAS_BIAS, bool DO_GELU, int NN>
__device__ __forceinline__ void gemm8_body(const u16* __restrict__ A, const u16* __restrict__ BR,
                                           const void* bias, long bias_off,
                                           u16* __restrict__ outp,
                                           const int* __restrict__ dtflag) {
  constexpr int NKT = GK >> 6;   // 8
  constexpr int N16 = NN >> 4;
  int lane = threadIdx.x & 63;
  int w = threadIdx.x >> 6;       // wave 0..7
  int wm = w >> 2, wn = w & 3;    // 2 x 4
  int m0 = blockIdx.x * 256;
  int n0 = blockIdx.y * 256;
  int n016 = blockIdx.y * 16;

  __shared__ alignas(16) u16 smem8[65536];  // 2 bufs x (A 32KB | B 32KB) = 128 KiB

  int arow = lane >> 3;
  int acu = ((lane & 7) ^ arow) * 8;
  const u16* Ag0 = A + (size_t)(m0 + (w * 2 + 0) * 8 + arow) * GK + acu;
  const u16* Ag1 = A + (size_t)(m0 + (w * 2 + 1) * 8 + arow) * GK + acu;
  const u16* Bg = BR + (size_t)n016 * 512 + lane * 8;

  auto stage_full = [&](int kt, int dbuf) {
    u16* aD = smem8 + dbuf * 32768;
    u16* bD = aD + 16384;
    size_t go = (size_t)kt * 64;
#pragma unroll
    for (int half = 0; half < 2; ++half) {
      ld16(Ag0 + (size_t)half * 128 * GK + go, aD + half * 8192 + (w * 2 + 0) * 512);
      ld16(Ag1 + (size_t)half * 128 * GK + go, aD + half * 8192 + (w * 2 + 1) * 512);
    }
#pragma unroll
    for (int kk = 0; kk < 2; ++kk) {
      const u16* s = Bg + ((size_t)(kt * 2 + kk) * N16) * 512;
      ld16(s + (size_t)w * 512,       bD + kk * 8192 + (0 + w) * 512);
      ld16(s + (size_t)(8 + w) * 512, bD + kk * 8192 + (8 + w) * 512);
    }
  };

  int aoff = (lane & 15) * 64;
  int axor = (lane & 7) << 3;
  int ak0 = ((lane >> 4) * 8) ^ axor;
  int ak1 = (32 + (lane >> 4) * 8) ^ axor;

  floatx4 acc[8][4];
#pragma unroll
  for (int mi = 0; mi < 8; ++mi)
#pragma unroll
    for (int j = 0; j < 4; ++j)
#pragma unroll
      for (int r = 0; r < 4; ++r) acc[mi][j][r] = 0.0f;

  stage_full(0, 0);
  stage_full(1, 1);
  ASM_VMCNT(8);
  __builtin_amdgcn_s_barrier();
  SBAR0();

#pragma unroll
  for (int c = 0; c < NKT; ++c) {
    const u16* aL = smem8 + (c & 1) * 32768;
    const u16* bL = aL + 16384;
#pragma unroll
    for (int kk = 0; kk < 2; ++kk) {
      int akh = kk ? ak1 : ak0;
      bf16x8 bfr[4];
#pragma unroll
      for (int i = 0; i < 4; ++i)
        bfr[i] = *(const bf16x8*)(bL + ((kk * 16 + wn * 4 + i) * 64 + lane) * 8);
#pragma unroll
      for (int mh = 0; mh < 2; ++mh) {
        bf16x8 afr[4];
#pragma unroll
        for (int i = 0; i < 4; ++i)
          afr[i] = *(const bf16x8*)(aL + (wm * 8 + mh * 4 + i) * 1024 + aoff + akh);
        __builtin_amdgcn_s_setprio(1);
#pragma unroll
        for (int mi = 0; mi < 4; ++mi)
#pragma unroll
          for (int j = 0; j < 4; ++j)
            acc[mh * 4 + mi][j] =
                __builtin_amdgcn_mfma_f32_16x16x32_bf16(afr[mi], bfr[j], acc[mh * 4 + mi][j], 0, 0, 0);
        __builtin_amdgcn_s_setprio(0);
      }
    }
    SBAR0();
    __builtin_amdgcn_s_barrier();        // A: all waves done reading live buf
    if (c + 2 < NKT) {
      stage_full(c + 2, c & 1);
      ASM_VMCNT(8);                      // tile c+1 landed; c+2 stays in flight
    } else if (c + 1 < NKT) {
      ASM_VMCNT(0);
    }
    __builtin_amdgcn_s_barrier();        // B: landing cross-wave
    SBAR0();
  }

  ASM_VMCNT(0);
  __builtin_amdgcn_s_barrier();

  // ---- epilogue: single-shot bf16 staging (per-wave 128x64 = 16KB, 8x = 128KB) ----
  u16* epw = smem8 + w * 8192;
  int dtv = HAS_BIAS ? *dtflag : 0;
  int nW = n0 + wn * 64;
  int mW = m0 + wm * 128;
  float bv[4];
#pragma unroll
  for (int j = 0; j < 4; ++j)
    bv[j] = HAS_BIAS ? ldin(bias, bias_off + nW + j * 16 + (lane & 15), dtv) : 0.0f;
#pragma unroll
  for (int mf = 0; mf < 8; ++mf)
#pragma unroll
    for (int j = 0; j < 4; ++j)
#pragma unroll
      for (int r = 0; r < 4; ++r) {
        float v = acc[mf][j][r] + bv[j];
        if (DO_GELU) v = fast_gelu(v);
        int row = mf * 16 + (lane >> 4) * 4 + r;
        int s = (row >> 2) & 3;
        int col = (j * 16 + (lane & 15)) ^ (s << 3);
        epw[row * 64 + col] = f2b(v);
      }
  asm volatile("s_waitcnt lgkmcnt(0)" ::: "memory");
#pragma unroll
  for (int p = 0; p < 16; ++p) {
    int row = p * 8 + (lane >> 3);
    int s = (row >> 2) & 3;
    int g = (lane & 7) ^ s;
    uint4 pk = *(const uint4*)(epw + row * 64 + g * 8);
    size_t gi = (size_t)(mW + row) * NN + nW + (lane & 7) * 8;
    *(uint4*)&outp[gi] = pk;
  }
}

// separately-named instantiations (independent codegen, distinct profile rows)
__global__ __launch_bounds__(512, 2) void k_g8a(const u16* __restrict__ A, const u16* __restrict__ BR,
                                                u16* __restrict__ outp, const int* dtflag) {
  gemm8_body<false, false, QKVW>(A, BR, nullptr, 0, outp, dtflag);
}
__global__ __launch_bounds__(512, 2) void k_g8b(const u16* __restrict__ A, const u16* __restrict__ BR,
                                                const void* bias, long bias_off,
                                                u16* __restrict__ outp, const int* dtflag) {
  gemm8_body<true, true, FFDIM>(A, BR, bias, bias_off, outp, dtflag);
}

// ---------------- attention phase A v2: MFMA exp(K)^T @ V ----------------
__global__ __launch_bounds__(256) void k_attnA(const u16* __restrict__ qkv,
                                               float* __restrict__ Ksum, float* __restrict__ KV) {
  int u = blockIdx.x & 63;
  int bh = blockIdx.x >> 6;
  int head = bh & 7, batch = bh >> 3;
  int t = threadIdx.x;
  __shared__ u16 ekt[4096];   // ekt[d][p^swz] = bf16(exp(k[p][d]))
  __shared__ u16 vt[4096];    // vt[e][p^swz]  = v[p][e]
  __shared__ float ks4[4][64];
  {
    int pr = t >> 2, s = t & 3;
    const u16* base = qkv + (size_t)(batch * SEQ + u * 64 + pr) * QKVW + head * DH;
    uint4 kp0 = *(const uint4*)(base + 512 + s * 16);
    uint4 kp1 = *(const uint4*)(base + 512 + s * 16 + 8);
    uint4 vp0 = *(const uint4*)(base + 1024 + s * 16);
    uint4 vp1 = *(const uint4*)(base + 1024 + s * 16 + 8);
    float kf[16];
    unpk8(kp0, kf); unpk8(kp1, kf + 8);
    u16 vu[16];
    vu[0] = (u16)vp0.x; vu[1] = (u16)(vp0.x >> 16); vu[2] = (u16)vp0.y; vu[3] = (u16)(vp0.y >> 16);
    vu[4] = (u16)vp0.z; vu[5] = (u16)(vp0.z >> 16); vu[6] = (u16)vp0.w; vu[7] = (u16)(vp0.w >> 16);
    vu[8] = (u16)vp1.x; vu[9] = (u16)(vp1.x >> 16); vu[10] = (u16)vp1.y; vu[11] = (u16)(vp1.y >> 16);
    vu[12] = (u16)vp1.z; vu[13] = (u16)(vp1.z >> 16); vu[14] = (u16)vp1.w; vu[15] = (u16)(vp1.w >> 16);
#pragma unroll
    for (int i = 0; i < 16; ++i) {
      int row = s * 16 + i;
      int col = pr ^ ((i & 7) << 3);
      ekt[row * 64 + col] = f2b(expf(fminf(kf[i], 30.0f)));
      vt[row * 64 + col] = vu[i];
    }
  }
  __syncthreads();
  int w = t >> 6, l = t & 63;
  int X = (l & 7) << 3;
  // Ksum partials: wave w sums p-quarter w for d=l
  {
    uint4 e0 = *(const uint4*)(ekt + l * 64 + ((w * 16) ^ X));
    uint4 e1 = *(const uint4*)(ekt + l * 64 + ((w * 16 + 8) ^ X));
    float f0[8], f1[8];
    unpk8(e0, f0); unpk8(e1, f1);
    float ssum = 0.0f;
#pragma unroll
    for (int i = 0; i < 8; ++i) ssum += f0[i] + f1[i];
    ks4[w][l] = ssum;
  }
  // MFMA: KV[d][e] = sum_p expk[p][d] * v[p][e]
  floatx4 acc[4];
#pragma unroll
  for (int nf = 0; nf < 4; ++nf)
#pragma unroll
    for (int r = 0; r < 4; ++r) acc[nf][r] = 0.0f;
  int dl = w * 16 + (l & 15);
#pragma unroll
  for (int kc = 0; kc < 2; ++kc) {
    int poff = kc * 32 + (l >> 4) * 8;
    bf16x8 afr = *(const bf16x8*)(ekt + dl * 64 + (poff ^ X));
#pragma unroll
    for (int nf = 0; nf < 4; ++nf) {
      bf16x8 bfr = *(const bf16x8*)(vt + (nf * 16 + (l & 15)) * 64 + (poff ^ X));
      acc[nf] = __builtin_amdgcn_mfma_f32_16x16x32_bf16(afr, bfr, acc[nf], 0, 0, 0);
    }
  }
  float* kvout = KV + (size_t)blockIdx.x * 4096;
#pragma unroll
  for (int nf = 0; nf < 4; ++nf)
#pragma unroll
    for (int r = 0; r < 4; ++r) {
      int d = w * 16 + (l >> 4) * 4 + r;
      kvout[d * 64 + nf * 16 + (l & 15)] = acc[nf][r];
    }
  __syncthreads();
  if (t < 64) Ksum[(size_t)blockIdx.x * 64 + t] = ks4[0][t] + ks4[1][t] + ks4[2][t] + ks4[3][t];
}

// ---------------- attention phase B: exclusive prefix over buckets ----------------
__global__ __launch_bounds__(64) void k_scan2(float* __restrict__ Ksum, float* __restrict__ KV) {
  int bh = blockIdx.x >> 6;
  int d = blockIdx.x & 63;
  int e = threadIdx.x;
  float* p0 = KV + (size_t)bh * 64 * 4096 + d * 64 + e;
  float v[64];
#pragma unroll
  for (int u = 0; u < 64; ++u) v[u] = p0[(size_t)u * 4096];
  float run = 0.0f;
#pragma unroll
  for (int u = 0; u < 64; ++u) { float c = v[u]; v[u] = run; run += c; }
#pragma unroll
  for (int u = 0; u < 64; ++u) p0[(size_t)u * 4096] = v[u];
  if (d == 0) {
    float* kp = Ksum + (size_t)bh * 4096 + e;
    float sv[64];
#pragma unroll
    for (int u = 0; u < 64; ++u) sv[u] = kp[u * 64];
    float r = 0.0f;
#pragma unroll
    for (int u = 0; u < 64; ++u) { float c = sv[u]; sv[u] = r; r += c; }
#pragma unroll
    for (int u = 0; u < 64; ++u) kp[u * 64] = sv[u];
  }
}

// ---------------- attention phase C v2: MFMA softmax(q) @ context ----------------
__global__ __launch_bounds__(256) void k_attnC(const u16* __restrict__ qkv, const float* __restrict__ Ksum,
                                               const float* __restrict__ KV, u16* __restrict__ att) {
  int u = blockIdx.x & 63;
  int bh = blockIdx.x >> 6;
  int head = bh & 7, batch = bh >> 3;
  int t = threadIdx.x;
  int pos = t >> 2, s = t & 3;
  __shared__ u16 cmt[4096];   // cmt[e][d^swz] = bf16(Cm[d][e])
  __shared__ u16 qst[4096];   // qst[n][d^swz] = bf16(qs[n][d])
  __shared__ float S[64];
  __shared__ float dinv[64];
  {
    const float* kvb = KV + (size_t)blockIdx.x * 4096 + pos * 64 + s * 16;
    float cf[16];
#pragma unroll
    for (int i4 = 0; i4 < 4; ++i4) {
      float4 c4 = *(const float4*)(kvb + i4 * 4);
      cf[i4 * 4 + 0] = c4.x; cf[i4 * 4 + 1] = c4.y; cf[i4 * 4 + 2] = c4.z; cf[i4 * 4 + 3] = c4.w;
    }
#pragma unroll
    for (int i = 0; i < 16; ++i)
      cmt[(s * 16 + i) * 64 + (pos ^ ((i & 7) << 3))] = f2b(cf[i]);
  }
  if (t < 64) S[t] = Ksum[(size_t)blockIdx.x * 64 + t];
  size_t grow = (size_t)(batch * SEQ + u * 64 + pos) * QKVW + head * DH;
  uint4 q0 = *(const uint4*)(qkv + grow + s * 16);
  uint4 q1 = *(const uint4*)(qkv + grow + s * 16 + 8);
  float q[16];
  unpk8(q0, q); unpk8(q1, q + 8);
  float mx = q[0];
#pragma unroll
  for (int i = 1; i < 16; ++i) mx = fmaxf(mx, q[i]);
  mx = fmaxf(mx, __shfl_xor(mx, 1));
  mx = fmaxf(mx, __shfl_xor(mx, 2));
  float sum = 0.0f;
#pragma unroll
  for (int i = 0; i < 16; ++i) { q[i] = expf(q[i] - mx); sum += q[i]; }
  sum += __shfl_xor(sum, 1);
  sum += __shfl_xor(sum, 2);
  float scale = 0.125f / sum;  // * e^-0.5 with e=64
#pragma unroll
  for (int i = 0; i < 16; ++i) q[i] *= scale;
  {
    uint4 pa, pb;
    pa.x = (unsigned)f2b(q[0]) | ((unsigned)f2b(q[1]) << 16);
    pa.y = (unsigned)f2b(q[2]) | ((unsigned)f2b(q[3]) << 16);
    pa.z = (unsigned)f2b(q[4]) | ((unsigned)f2b(q[5]) << 16);
    pa.w = (unsigned)f2b(q[6]) | ((unsigned)f2b(q[7]) << 16);
    pb.x = (unsigned)f2b(q[8]) | ((unsigned)f2b(q[9]) << 16);
    pb.y = (unsigned)f2b(q[10]) | ((unsigned)f2b(q[11]) << 16);
    pb.z = (unsigned)f2b(q[12]) | ((unsigned)f2b(q[13]) << 16);
    pb.w = (unsigned)f2b(q[14]) | ((unsigned)f2b(q[15]) << 16);
    int Xp = (pos & 7) << 3;
    *(uint4*)(qst + pos * 64 + ((s * 16) ^ Xp)) = pa;
    *(uint4*)(qst + pos * 64 + ((s * 16 + 8) ^ Xp)) = pb;
  }
  __syncthreads();  // cmt, qst, S ready
  float Dp = 0.0f;
#pragma unroll
  for (int i = 0; i < 16; ++i) Dp += q[i] * S[s * 16 + i];
  Dp += __shfl_xor(Dp, 1);
  Dp += __shfl_xor(Dp, 2);
  if (s == 0) dinv[pos] = 1.0f / fmaxf(Dp, 1e-3f);
  int w = t >> 6, l = t & 63;
  int X = (l & 7) << 3;
  int nl = w * 16 + (l & 15);
  floatx4 acc[4];
#pragma unroll
  for (int nf = 0; nf < 4; ++nf)
#pragma unroll
    for (int r = 0; r < 4; ++r) acc[nf][r] = 0.0f;
#pragma unroll
  for (int kc = 0; kc < 2; ++kc) {
    int doff = kc * 32 + (l >> 4) * 8;
    bf16x8 afr = *(const bf16x8*)(qst + nl * 64 + (doff ^ X));
#pragma unroll
    for (int nf = 0; nf < 4; ++nf) {
      bf16x8 bfr = *(const bf16x8*)(cmt + (nf * 16 + (l & 15)) * 64 + (doff ^ X));
      acc[nf] = __builtin_amdgcn_mfma_f32_16x16x32_bf16(afr, bfr, acc[nf], 0, 0, 0);
    }
  }
  __syncthreads();  // dinv ready
  u16* ob = att + (size_t)(batch * SEQ + u * 64) * DIM + head * DH;
#pragma unroll
  for (int r = 0; r < 4; ++r) {
    int n = w * 16 + (l >> 4) * 4 + r;
    float dv = dinv[n];
#pragma unroll
    for (int nf = 0; nf < 4; ++nf)
      ob[(size_t)n * DIM + nf * 16 + (l & 15)] = f2b(acc[nf][r] * dv);
  }
}

// ---------------- host orchestration ----------------
extern "C" void kernel_launch(void* const* d_in, const int* in_sizes, int n_in,
                              void* d_out, int out_size, void* d_ws, size_t ws_size,
                              hipStream_t stream) {
  (void)in_sizes; (void)n_in; (void)out_size; (void)ws_size;
  const void* x_in = d_in[0];
  const void* ln1_g = d_in[1];
  const void* ln1_b = d_in[2];
  const void* wq = d_in[3];
  const void* wk = d_in[4];
  const void* wv = d_in[5];
  const void* wo = d_in[6];
  const void* bo = d_in[7];
  const void* ln2_g = d_in[8];
  const void* ln2_b = d_in[9];
  const void* w1 = d_in[10];
  const void* b1 = d_in[11];
  const void* w2 = d_in[12];
  const void* b2 = d_in[13];

  char* ws = (char*)d_ws;
  float* xf = (float*)(ws);              // 16 MiB f32 residual
  u16* h = (u16*)(ws + 16777216);        // 8 MiB bf16
  u16* region = (u16*)(ws + 25165824);   // 32 MiB: qkv (24 MiB) / gb (32 MiB)
  float* Ksum = (float*)(ws + 58720256); // 256 KiB
  float* KV = (float*)(ws + 58982400);   // 16 MiB
  u16* WR = (u16*)(ws + 75759616);       // 24 MiB repacked weights
  int* dt = (int*)(ws + 100925440);      // dtype flag
  u16* qkv = region;
  u16* gb = region;

  auto WqkvR = [&](int i) { return WR + (size_t)i * LSTRIDE + 0; };
  auto WoR   = [&](int i) { return WR + (size_t)i * LSTRIDE + 786432; };
  auto W1R   = [&](int i) { return WR + (size_t)i * LSTRIDE + 1048576; };
  auto W2R   = [&](int i) { return WR + (size_t)i * LSTRIDE + 2097152; };

  k_detect<<<dim3(1), dim3(1), 0, stream>>>(ln1_g, dt);

  const int nx = ROWS * DIM;
  k_x2f<<<dim3((nx + 255) / 256), dim3(256), 0, stream>>>(x_in, xf, nx, dt);

  k_repackQ<<<dim3(16, 8, 16), dim3(256), 0, stream>>>(wq, wk, wv, wo, WR, dt);
  k_repackF1<<<dim3(16, 32, 4), dim3(256), 0, stream>>>(w1, WR, dt);
  k_repackF2<<<dim3(64, 8, 4), dim3(256), 0, stream>>>(w2, WR, dt);

  for (int i = 0; i < 4; ++i) {
    // PreNorm(attn)
    k_ln<<<dim3(ROWS), dim3(256), 0, stream>>>(xf, ln1_g, ln1_b, (long)i * DIM, h, dt);
    // fused QKV gemm: [8192,512] @ [512,1536] — round-8 proven 256x256 config
    k_g8a<<<dim3(32, 6), dim3(512), 0, stream>>>(h, WqkvR(i), qkv, dt);
    k_attnA<<<dim3(1024), dim3(256), 0, stream>>>(qkv, Ksum, KV);
    k_scan2<<<dim3(1024), dim3(64), 0, stream>>>(Ksum, KV);
    k_attnC<<<dim3(1024), dim3(256), 0, stream>>>(qkv, Ksum, KV, h);  // att -> h
    // x += att @ wo + bo  (N=512, K=512) — v8 2-wave 128x64, 512 blocks
    k_gemm2w<512><<<dim3(64, 8), dim3(128), 0, stream>>>(h, WoR(i), bo, (long)i * DIM, xf, xf, dt);
    // PreNorm(FF)
    k_ln<<<dim3(ROWS), dim3(256), 0, stream>>>(xf, ln2_g, ln2_b, (long)i * DIM, h, dt);
    // FF up: [8192,512] @ [512,2048] + bias + gelu
    k_g8b<<<dim3(32, 8), dim3(512), 0, stream>>>(h, W1R(i), b1, (long)i * FFDIM, gb, dt);
    // FF down: [8192,2048] @ [2048,512] + bias + residual — v8 2-wave 128x64
    k_gemm2w<2048><<<dim3(64, 8), dim3(128), 0, stream>>>(gb, W2R(i), b2, (long)i * DIM, xf, xf, dt);
  }

  k_store<<<dim3((nx + 255) / 256), dim3(256), 0, stream>>>(xf, d_out, nx, dt);
}

// Round 11
// 665.540 us; speedup vs baseline: 1.3065x; 1.3065x over previous
//
#include <hip/hip_runtime.h>

// ---------------- types / helpers ----------------
typedef unsigned short u16;
typedef __bf16 bf16x8 __attribute__((ext_vector_type(8)));
typedef float floatx4 __attribute__((ext_vector_type(4)));

#define DIM 512
#define HEADS 8
#define DH 64
#define SEQ 4096
#define BATCH 2
#define ROWS (BATCH * SEQ) /* 8192 */
#define FFDIM 2048
#define QKVW 1536 /* fused qkv row width */
#define LSTRIDE 3145728L /* repacked weight elems per layer */
#define GK 512   /* K of all gemm8 GEMMs (QKV, W1) */

#define SBAR0() __builtin_amdgcn_sched_barrier(0)
#define ASM_VMCNT(n) asm volatile("s_waitcnt vmcnt(" #n ")" ::: "memory")

__device__ __forceinline__ float b2f(u16 u) {
  union { float f; unsigned int i; } c; c.i = ((unsigned int)u) << 16; return c.f;
}
__device__ __forceinline__ u16 f2b(float f) {
  union { float f; unsigned int i; } c; c.f = f;
  unsigned int r = c.i + 0x7FFFu + ((c.i >> 16) & 1u);
  return (u16)(r >> 16);
}
__device__ __forceinline__ float ldin(const void* p, long i, int bf) {
  return bf ? b2f(((const u16*)p)[i]) : ((const float*)p)[i];
}
// async global->LDS, 16 bytes/lane. LDS dest = base + lane*16 (HW); global addr per-lane.
__device__ __forceinline__ void ld16(const u16* g, u16* l) {
  __builtin_amdgcn_global_load_lds((const __attribute__((address_space(1))) void*)g,
                                   (__attribute__((address_space(3))) void*)l, 16, 0, 0);
}
// unpack 8 u16 (as uint4) -> 8 floats
__device__ __forceinline__ void unpk8(uint4 p, float* o) {
  o[0] = b2f((u16)(p.x & 0xFFFF)); o[1] = b2f((u16)(p.x >> 16));
  o[2] = b2f((u16)(p.y & 0xFFFF)); o[3] = b2f((u16)(p.y >> 16));
  o[4] = b2f((u16)(p.z & 0xFFFF)); o[5] = b2f((u16)(p.z >> 16));
  o[6] = b2f((u16)(p.w & 0xFFFF)); o[7] = b2f((u16)(p.w >> 16));
}
// exact-enough GELU: erf via Abramowitz-Stegun 7.1.26 (|err| <= 1.5e-7) + fast exp.
__device__ __forceinline__ float fast_gelu(float v) {
  float z = fabsf(v) * 0.70710678118654752f;
  float t = 1.0f / (1.0f + 0.3275911f * z);
  float p = t * (0.254829592f +
           t * (-0.284496736f +
           t * (1.421413741f +
           t * (-1.453152027f +
           t * 1.061405429f))));
  float e = __expf(-z * z);
  float er = 1.0f - p * e;             // erf(|z|)
  float s = copysignf(er, v);          // erf(z)
  return 0.5f * v * (1.0f + s);
}

// ---------------- dtype detection ----------------
__global__ void k_detect(const void* __restrict__ g, int* __restrict__ flag) {
  *flag = (((const u16*)g)[0] == 0x3F80u) ? 1 : 0;
}

// ---------------- input x -> f32 / f32 -> out ----------------
__global__ __launch_bounds__(256) void k_x2f(const void* __restrict__ in, float* __restrict__ out,
                                             int n, const int* __restrict__ dt) {
  int bf = *dt;
  int i = blockIdx.x * 256 + threadIdx.x;
  if (i < n) out[i] = ldin(in, i, bf);
}
__global__ __launch_bounds__(256) void k_store(const float* __restrict__ in, void* __restrict__ out,
                                               int n, const int* __restrict__ dt) {
  int bf = *dt;
  int i = blockIdx.x * 256 + threadIdx.x;
  if (i < n) {
    if (bf) ((u16*)out)[i] = f2b(in[i]);
    else ((float*)out)[i] = in[i];
  }
}

// ---------------- weight repack (LDS-tiled, coalesced, batched) ----------------
__device__ __forceinline__ void repack_tile(const void* W, long w_off, u16* R, int N,
                                            int n16tot, int j_off, int kb, int jb, int bf) {
  int t = threadIdx.x;
  __shared__ float tile[32][65];
  int r0 = t >> 6;
  int c = t & 63;
#pragma unroll
  for (int i = 0; i < 8; ++i) {
    int rr = i * 4 + r0;
    tile[rr][c] = ldin(W, w_off + (long)(kb * 32 + rr) * N + jb * 64 + c, bf);
  }
  __syncthreads();
  int lane = t & 63, w = t >> 6;
  alignas(16) u16 tmp[8];
#pragma unroll
  for (int r = 0; r < 8; ++r) tmp[r] = f2b(tile[(lane >> 4) * 8 + r][w * 16 + (lane & 15)]);
  long oidx = (((long)kb * n16tot + j_off + jb * 4 + w) * 64 + lane) * 8;
  *(uint4*)(R + oidx) = *(const uint4*)tmp;
}
// all 512x512 weights: grid (16,8,16); z = layer*4 + type(0=q,1=k,2=v,3=o)
__global__ __launch_bounds__(256) void k_repackQ(const void* wq, const void* wk,
                                                 const void* wv, const void* wo,
                                                 u16* WR, const int* __restrict__ dt) {
  int bf = *dt;
  int z = blockIdx.z, layer = z >> 2, type = z & 3;
  const void* W = (type == 0) ? wq : (type == 1) ? wk : (type == 2) ? wv : wo;
  u16* R = WR + (long)layer * LSTRIDE + (type < 3 ? 0 : 786432);
  int n16tot = (type < 3) ? 96 : 32;
  int j_off = (type < 3) ? type * 32 : 0;
  repack_tile(W, (long)layer * 262144, R, 512, n16tot, j_off, blockIdx.x, blockIdx.y, bf);
}
// w1: grid (16,32,4)
__global__ __launch_bounds__(256) void k_repackF1(const void* w1, u16* WR, const int* __restrict__ dt) {
  int bf = *dt;
  repack_tile(w1, (long)blockIdx.z * 1048576, WR + (long)blockIdx.z * LSTRIDE + 1048576,
              2048, 128, 0, blockIdx.x, blockIdx.y, bf);
}
// w2: grid (64,8,4)
__global__ __launch_bounds__(256) void k_repackF2(const void* w2, u16* WR, const int* __restrict__ dt) {
  int bf = *dt;
  repack_tile(w2, (long)blockIdx.z * 1048576, WR + (long)blockIdx.z * LSTRIDE + 2097152,
              512, 32, 0, blockIdx.x, blockIdx.y, bf);
}

// ---------------- layernorm (f32 in, bf16 out) ----------------
__global__ __launch_bounds__(256) void k_ln(const float* __restrict__ x,
                                            const void* __restrict__ g, const void* __restrict__ b,
                                            long gb_off, u16* __restrict__ out,
                                            const int* __restrict__ dt) {
  int bf = *dt;
  int row = blockIdx.x;
  int t = threadIdx.x;
  const float* xr = x + (size_t)row * DIM;
  float v0 = xr[t], v1 = xr[t + 256];
  float s = v0 + v1;
  float s2 = v0 * v0 + v1 * v1;
#pragma unroll
  for (int off = 32; off > 0; off >>= 1) {
    s += __shfl_down(s, off);
    s2 += __shfl_down(s2, off);
  }
  __shared__ float red[8];
  int lane = t & 63, w = t >> 6;
  if (lane == 0) { red[w] = s; red[4 + w] = s2; }
  __syncthreads();
  float ts = red[0] + red[1] + red[2] + red[3];
  float ts2 = red[4] + red[5] + red[6] + red[7];
  float mean = ts * (1.0f / DIM);
  float var = ts2 * (1.0f / DIM) - mean * mean;
  float rstd = rsqrtf(var + 1e-5f);
  u16* orow = out + (size_t)row * DIM;
  orow[t] = f2b((v0 - mean) * rstd * ldin(g, gb_off + t, bf) + ldin(b, gb_off + t, bf));
  orow[t + 256] = f2b((v1 - mean) * rstd * ldin(g, gb_off + t + 256, bf) + ldin(b, gb_off + t + 256, bf));
}

// ---------------- MFMA GEMM v6 (N=512 GEMMs: WO K=512, W2 K=2048) ----------------
// Free-run (round-6 verified sync) + compile-time K (full unroll, static LDS addrs) +
// single-shot f32 epilogue (1 lgkm wait instead of 8). Block 256 = 4 waves 2m x 2n;
// tile 128x64; BK=64; always bias + residual + f32 out (the only users).
template <int TK>
__global__ __launch_bounds__(256) void k_gemm3(const u16* __restrict__ A, const u16* __restrict__ BR,
                                               const void* bias, long bias_off,
                                               const float* __restrict__ res, float* __restrict__ outp,
                                               const int* __restrict__ dtflag) {
  constexpr int NKT = TK >> 6;
  int lane = threadIdx.x & 63;
  int wid = threadIdx.x >> 6;
  int wm = wid & 1, wn = wid >> 1;
  int m0 = blockIdx.x * 128;
  int n0 = blockIdx.y * 64;
  int n016 = blockIdx.y * 4;
  constexpr int N16 = 32;  // 512 >> 4

  constexpr int BUFB = 24 * 1024;  // A 16KB + B 8KB per buffer
  __shared__ alignas(16) char smem[2 * BUFB];

  floatx4 acc[4][2];
#pragma unroll
  for (int mi = 0; mi < 4; ++mi)
#pragma unroll
    for (int j = 0; j < 2; ++j)
#pragma unroll
      for (int r = 0; r < 4; ++r) acc[mi][j][r] = 0.0f;

  // A staging: coalesced 8-row x 128B insts, pre-swizzled source
  int arow = lane >> 3;
  int acu = ((lane & 7) ^ arow) * 8;
  const u16* AgS = A + (size_t)(m0 + wid * 32 + arow) * TK + acu;

  auto stage = [&](int kb, int b) {
    u16* aL = (u16*)(smem + b * BUFB);
    u16* bL = aL + 8192;
#pragma unroll
    for (int j = 0; j < 4; ++j)
      ld16(AgS + (size_t)(j * 8) * TK + (size_t)kb * 64, aL + (wid * 4 + j) * 512);
    ld16(BR + (((size_t)(kb * 2) * N16 + n016 + wid) * 64 + lane) * 8, bL + wid * 512);
    ld16(BR + (((size_t)(kb * 2 + 1) * N16 + n016 + wid) * 64 + lane) * 8, bL + 2048 + wid * 512);
  };

  // swizzled A-read offsets (u16)
  int aoff = (lane & 15) * 64;
  int axor = (lane & 7) << 3;
  int ak0 = ((lane >> 4) * 8) ^ axor;
  int ak1 = (32 + (lane >> 4) * 8) ^ axor;

  stage(0, 0);
  stage(1, 1);
  ASM_VMCNT(6);
  __builtin_amdgcn_s_barrier();
  SBAR0();

#pragma unroll
  for (int kb = 0; kb < NKT; ++kb) {
    const u16* aL = (const u16*)(smem + (kb & 1) * BUFB);
    const u16* bL = aL + 8192;
#pragma unroll
    for (int h = 0; h < 2; ++h) {
      int akh = h ? ak1 : ak0;
      bf16x8 afr[4], bfr[2];
#pragma unroll
      for (int mi = 0; mi < 4; ++mi)
        afr[mi] = *(const bf16x8*)(aL + (wm * 4 + mi) * 1024 + aoff + akh);
#pragma unroll
      for (int j = 0; j < 2; ++j)
        bfr[j] = *(const bf16x8*)(bL + h * 2048 + ((wn * 2 + j) * 64 + lane) * 8);
      __builtin_amdgcn_s_setprio(1);
#pragma unroll
      for (int mi = 0; mi < 4; ++mi)
#pragma unroll
        for (int j = 0; j < 2; ++j)
          acc[mi][j] = __builtin_amdgcn_mfma_f32_16x16x32_bf16(afr[mi], bfr[j], acc[mi][j], 0, 0, 0);
      __builtin_amdgcn_s_setprio(0);
    }
    SBAR0();
    __builtin_amdgcn_s_barrier();        // A: all waves done reading live buf
    if (kb + 2 < NKT) {
      stage(kb + 2, kb & 1);
      ASM_VMCNT(6);                      // tile kb+1 landed; kb+2 in flight
    } else if (kb + 1 < NKT) {
      ASM_VMCNT(0);
    }
    __builtin_amdgcn_s_barrier();        // B: landing cross-wave
    SBAR0();
  }

  // ---- epilogue v6: single-shot f32 staging, group-XOR swizzled, 1 wait ----
  float* epf = (float*)smem + wid * 2048;
  int dtv = *dtflag;
  int nW = n0 + wn * 32;
  int mWb = m0 + wm * 64;
  float bv[2];
#pragma unroll
  for (int j = 0; j < 2; ++j)
    bv[j] = ldin(bias, bias_off + nW + j * 16 + (lane & 15), dtv);
#pragma unroll
  for (int mi = 0; mi < 4; ++mi)
#pragma unroll
    for (int j = 0; j < 2; ++j)
#pragma unroll
      for (int r = 0; r < 4; ++r) {
        int row = mi * 16 + (lane >> 4) * 4 + r;
        int s = (row >> 2) & 3;
        int col = (j * 16 + (lane & 15)) ^ (s << 2);
        epf[row * 32 + col] = acc[mi][j][r] + bv[j];
      }
  asm volatile("s_waitcnt lgkmcnt(0)" ::: "memory");
#pragma unroll
  for (int p = 0; p < 8; ++p) {
    int row = p * 8 + (lane >> 3);
    int s = (row >> 2) & 3;
    int g = (lane & 7) ^ s;
    float4 v = *(const float4*)(epf + row * 32 + g * 4);
    size_t gi = (size_t)(mWb + row) * DIM + nW + (lane & 7) * 4;
    float4 rv = *(const float4*)&res[gi];
    v.x += rv.x; v.y += rv.y; v.z += rv.z; v.w += rv.w;
    *(float4*)&outp[gi] = v;
  }
}

// ---------------- MFMA GEMM v6: 256x256 free-run pipeline (QKV, W1), K=512 ----------
template <bool HAS_BIAS, bool DO_GELU, int NN>
__device__ __forceinline__ void gemm8_body(const u16* __restrict__ A, const u16* __restrict__ BR,
                                           const void* bias, long bias_off,
                                           u16* __restrict__ outp,
                                           const int* __restrict__ dtflag) {
  constexpr int NKT = GK >> 6;   // 8
  constexpr int N16 = NN >> 4;
  int lane = threadIdx.x & 63;
  int w = threadIdx.x >> 6;       // wave 0..7
  int wm = w >> 2, wn = w & 3;    // 2 x 4
  int m0 = blockIdx.x * 256;
  int n0 = blockIdx.y * 256;
  int n016 = blockIdx.y * 16;

  __shared__ alignas(16) u16 smem8[65536];  // 2 bufs x (A 32KB | B 32KB) = 128 KiB

  int arow = lane >> 3;
  int acu = ((lane & 7) ^ arow) * 8;
  const u16* Ag0 = A + (size_t)(m0 + (w * 2 + 0) * 8 + arow) * GK + acu;
  const u16* Ag1 = A + (size_t)(m0 + (w * 2 + 1) * 8 + arow) * GK + acu;
  const u16* Bg = BR + (size_t)n016 * 512 + lane * 8;

  auto stage_full = [&](int kt, int dbuf) {
    u16* aD = smem8 + dbuf * 32768;
    u16* bD = aD + 16384;
    size_t go = (size_t)kt * 64;
#pragma unroll
    for (int half = 0; half < 2; ++half) {
      ld16(Ag0 + (size_t)half * 128 * GK + go, aD + half * 8192 + (w * 2 + 0) * 512);
      ld16(Ag1 + (size_t)half * 128 * GK + go, aD + half * 8192 + (w * 2 + 1) * 512);
    }
#pragma unroll
    for (int kk = 0; kk < 2; ++kk) {
      const u16* s = Bg + ((size_t)(kt * 2 + kk) * N16) * 512;
      ld16(s + (size_t)w * 512,       bD + kk * 8192 + (0 + w) * 512);
      ld16(s + (size_t)(8 + w) * 512, bD + kk * 8192 + (8 + w) * 512);
    }
  };

  int aoff = (lane & 15) * 64;
  int axor = (lane & 7) << 3;
  int ak0 = ((lane >> 4) * 8) ^ axor;
  int ak1 = (32 + (lane >> 4) * 8) ^ axor;

  floatx4 acc[8][4];
#pragma unroll
  for (int mi = 0; mi < 8; ++mi)
#pragma unroll
    for (int j = 0; j < 4; ++j)
#pragma unroll
      for (int r = 0; r < 4; ++r) acc[mi][j][r] = 0.0f;

  stage_full(0, 0);
  stage_full(1, 1);
  ASM_VMCNT(8);
  __builtin_amdgcn_s_barrier();
  SBAR0();

#pragma unroll
  for (int c = 0; c < NKT; ++c) {
    const u16* aL = smem8 + (c & 1) * 32768;
    const u16* bL = aL + 16384;
#pragma unroll
    for (int kk = 0; kk < 2; ++kk) {
      int akh = kk ? ak1 : ak0;
      bf16x8 bfr[4];
#pragma unroll
      for (int i = 0; i < 4; ++i)
        bfr[i] = *(const bf16x8*)(bL + ((kk * 16 + wn * 4 + i) * 64 + lane) * 8);
#pragma unroll
      for (int mh = 0; mh < 2; ++mh) {
        bf16x8 afr[4];
#pragma unroll
        for (int i = 0; i < 4; ++i)
          afr[i] = *(const bf16x8*)(aL + (wm * 8 + mh * 4 + i) * 1024 + aoff + akh);
        __builtin_amdgcn_s_setprio(1);
#pragma unroll
        for (int mi = 0; mi < 4; ++mi)
#pragma unroll
          for (int j = 0; j < 4; ++j)
            acc[mh * 4 + mi][j] =
                __builtin_amdgcn_mfma_f32_16x16x32_bf16(afr[mi], bfr[j], acc[mh * 4 + mi][j], 0, 0, 0);
        __builtin_amdgcn_s_setprio(0);
      }
    }
    SBAR0();
    __builtin_amdgcn_s_barrier();        // A: all waves done reading live buf
    if (c + 2 < NKT) {
      stage_full(c + 2, c & 1);
      ASM_VMCNT(8);                      // tile c+1 landed; c+2 stays in flight
    } else if (c + 1 < NKT) {
      ASM_VMCNT(0);
    }
    __builtin_amdgcn_s_barrier();        // B: landing cross-wave
    SBAR0();
  }

  ASM_VMCNT(0);
  __builtin_amdgcn_s_barrier();

  // ---- epilogue v6: single-shot bf16 staging (per-wave 128x64 = 16KB, 8x = 128KB) ----
  // write bf16 via ds_write_b16 at [row][col ^ (((row>>2)&3)<<3)] (8-col groups),
  // ONE lgkm wait, then 16 passes of conflict-free ds_read_b128 + dwordx4 store.
  u16* epw = smem8 + w * 8192;
  int dtv = HAS_BIAS ? *dtflag : 0;
  int nW = n0 + wn * 64;
  int mW = m0 + wm * 128;
  float bv[4];
#pragma unroll
  for (int j = 0; j < 4; ++j)
    bv[j] = HAS_BIAS ? ldin(bias, bias_off + nW + j * 16 + (lane & 15), dtv) : 0.0f;
#pragma unroll
  for (int mf = 0; mf < 8; ++mf)
#pragma unroll
    for (int j = 0; j < 4; ++j)
#pragma unroll
      for (int r = 0; r < 4; ++r) {
        float v = acc[mf][j][r] + bv[j];
        if (DO_GELU) v = fast_gelu(v);
        int row = mf * 16 + (lane >> 4) * 4 + r;
        int s = (row >> 2) & 3;
        int col = (j * 16 + (lane & 15)) ^ (s << 3);
        epw[row * 64 + col] = f2b(v);
      }
  asm volatile("s_waitcnt lgkmcnt(0)" ::: "memory");
#pragma unroll
  for (int p = 0; p < 16; ++p) {
    int row = p * 8 + (lane >> 3);
    int s = (row >> 2) & 3;
    int g = (lane & 7) ^ s;
    uint4 pk = *(const uint4*)(epw + row * 64 + g * 8);
    size_t gi = (size_t)(mW + row) * NN + nW + (lane & 7) * 8;
    *(uint4*)&outp[gi] = pk;
  }
}

// separately-named instantiations (independent codegen, distinct profile rows)
__global__ __launch_bounds__(512, 2) void k_g8a(const u16* __restrict__ A, const u16* __restrict__ BR,
                                                u16* __restrict__ outp, const int* dtflag) {
  gemm8_body<false, false, QKVW>(A, BR, nullptr, 0, outp, dtflag);
}
__global__ __launch_bounds__(512, 2) void k_g8b(const u16* __restrict__ A, const u16* __restrict__ BR,
                                                const void* bias, long bias_off,
                                                u16* __restrict__ outp, const int* dtflag) {
  gemm8_body<true, true, FFDIM>(A, BR, bias, bias_off, outp, dtflag);
}

// ---------------- attention phase A v2: MFMA exp(K)^T @ V ----------------
__global__ __launch_bounds__(256) void k_attnA(const u16* __restrict__ qkv,
                                               float* __restrict__ Ksum, float* __restrict__ KV) {
  int u = blockIdx.x & 63;
  int bh = blockIdx.x >> 6;
  int head = bh & 7, batch = bh >> 3;
  int t = threadIdx.x;
  __shared__ u16 ekt[4096];   // ekt[d][p^swz] = bf16(exp(k[p][d]))
  __shared__ u16 vt[4096];    // vt[e][p^swz]  = v[p][e]
  __shared__ float ks4[4][64];
  {
    int pr = t >> 2, s = t & 3;
    const u16* base = qkv + (size_t)(batch * SEQ + u * 64 + pr) * QKVW + head * DH;
    uint4 kp0 = *(const uint4*)(base + 512 + s * 16);
    uint4 kp1 = *(const uint4*)(base + 512 + s * 16 + 8);
    uint4 vp0 = *(const uint4*)(base + 1024 + s * 16);
    uint4 vp1 = *(const uint4*)(base + 1024 + s * 16 + 8);
    float kf[16];
    unpk8(kp0, kf); unpk8(kp1, kf + 8);
    u16 vu[16];
    vu[0] = (u16)vp0.x; vu[1] = (u16)(vp0.x >> 16); vu[2] = (u16)vp0.y; vu[3] = (u16)(vp0.y >> 16);
    vu[4] = (u16)vp0.z; vu[5] = (u16)(vp0.z >> 16); vu[6] = (u16)vp0.w; vu[7] = (u16)(vp0.w >> 16);
    vu[8] = (u16)vp1.x; vu[9] = (u16)(vp1.x >> 16); vu[10] = (u16)vp1.y; vu[11] = (u16)(vp1.y >> 16);
    vu[12] = (u16)vp1.z; vu[13] = (u16)(vp1.z >> 16); vu[14] = (u16)vp1.w; vu[15] = (u16)(vp1.w >> 16);
#pragma unroll
    for (int i = 0; i < 16; ++i) {
      int row = s * 16 + i;
      int col = pr ^ ((i & 7) << 3);
      ekt[row * 64 + col] = f2b(expf(fminf(kf[i], 30.0f)));
      vt[row * 64 + col] = vu[i];
    }
  }
  __syncthreads();
  int w = t >> 6, l = t & 63;
  int X = (l & 7) << 3;
  // Ksum partials: wave w sums p-quarter w for d=l
  {
    uint4 e0 = *(const uint4*)(ekt + l * 64 + ((w * 16) ^ X));
    uint4 e1 = *(const uint4*)(ekt + l * 64 + ((w * 16 + 8) ^ X));
    float f0[8], f1[8];
    unpk8(e0, f0); unpk8(e1, f1);
    float ssum = 0.0f;
#pragma unroll
    for (int i = 0; i < 8; ++i) ssum += f0[i] + f1[i];
    ks4[w][l] = ssum;
  }
  // MFMA: KV[d][e] = sum_p expk[p][d] * v[p][e]
  floatx4 acc[4];
#pragma unroll
  for (int nf = 0; nf < 4; ++nf)
#pragma unroll
    for (int r = 0; r < 4; ++r) acc[nf][r] = 0.0f;
  int dl = w * 16 + (l & 15);
#pragma unroll
  for (int kc = 0; kc < 2; ++kc) {
    int poff = kc * 32 + (l >> 4) * 8;
    bf16x8 afr = *(const bf16x8*)(ekt + dl * 64 + (poff ^ X));
#pragma unroll
    for (int nf = 0; nf < 4; ++nf) {
      bf16x8 bfr = *(const bf16x8*)(vt + (nf * 16 + (l & 15)) * 64 + (poff ^ X));
      acc[nf] = __builtin_amdgcn_mfma_f32_16x16x32_bf16(afr, bfr, acc[nf], 0, 0, 0);
    }
  }
  float* kvout = KV + (size_t)blockIdx.x * 4096;
#pragma unroll
  for (int nf = 0; nf < 4; ++nf)
#pragma unroll
    for (int r = 0; r < 4; ++r) {
      int d = w * 16 + (l >> 4) * 4 + r;
      kvout[d * 64 + nf * 16 + (l & 15)] = acc[nf][r];
    }
  __syncthreads();
  if (t < 64) Ksum[(size_t)blockIdx.x * 64 + t] = ks4[0][t] + ks4[1][t] + ks4[2][t] + ks4[3][t];
}

// ---------------- attention phase B: exclusive prefix over buckets ----------------
__global__ __launch_bounds__(64) void k_scan2(float* __restrict__ Ksum, float* __restrict__ KV) {
  int bh = blockIdx.x >> 6;
  int d = blockIdx.x & 63;
  int e = threadIdx.x;
  float* p0 = KV + (size_t)bh * 64 * 4096 + d * 64 + e;
  float v[64];
#pragma unroll
  for (int u = 0; u < 64; ++u) v[u] = p0[(size_t)u * 4096];
  float run = 0.0f;
#pragma unroll
  for (int u = 0; u < 64; ++u) { float c = v[u]; v[u] = run; run += c; }
#pragma unroll
  for (int u = 0; u < 64; ++u) p0[(size_t)u * 4096] = v[u];
  if (d == 0) {
    float* kp = Ksum + (size_t)bh * 4096 + e;
    float sv[64];
#pragma unroll
    for (int u = 0; u < 64; ++u) sv[u] = kp[u * 64];
    float r = 0.0f;
#pragma unroll
    for (int u = 0; u < 64; ++u) { float c = sv[u]; sv[u] = r; r += c; }
#pragma unroll
    for (int u = 0; u < 64; ++u) kp[u * 64] = sv[u];
  }
}

// ---------------- attention phase C v2: MFMA softmax(q) @ context ----------------
__global__ __launch_bounds__(256) void k_attnC(const u16* __restrict__ qkv, const float* __restrict__ Ksum,
                                               const float* __restrict__ KV, u16* __restrict__ att) {
  int u = blockIdx.x & 63;
  int bh = blockIdx.x >> 6;
  int head = bh & 7, batch = bh >> 3;
  int t = threadIdx.x;
  int pos = t >> 2, s = t & 3;
  __shared__ u16 cmt[4096];   // cmt[e][d^swz] = bf16(Cm[d][e])
  __shared__ u16 qst[4096];   // qst[n][d^swz] = bf16(qs[n][d])
  __shared__ float S[64];
  __shared__ float dinv[64];
  {
    const float* kvb = KV + (size_t)blockIdx.x * 4096 + pos * 64 + s * 16;
    float cf[16];
#pragma unroll
    for (int i4 = 0; i4 < 4; ++i4) {
      float4 c4 = *(const float4*)(kvb + i4 * 4);
      cf[i4 * 4 + 0] = c4.x; cf[i4 * 4 + 1] = c4.y; cf[i4 * 4 + 2] = c4.z; cf[i4 * 4 + 3] = c4.w;
    }
#pragma unroll
    for (int i = 0; i < 16; ++i)
      cmt[(s * 16 + i) * 64 + (pos ^ ((i & 7) << 3))] = f2b(cf[i]);
  }
  if (t < 64) S[t] = Ksum[(size_t)blockIdx.x * 64 + t];
  size_t grow = (size_t)(batch * SEQ + u * 64 + pos) * QKVW + head * DH;
  uint4 q0 = *(const uint4*)(qkv + grow + s * 16);
  uint4 q1 = *(const uint4*)(qkv + grow + s * 16 + 8);
  float q[16];
  unpk8(q0, q); unpk8(q1, q + 8);
  float mx = q[0];
#pragma unroll
  for (int i = 1; i < 16; ++i) mx = fmaxf(mx, q[i]);
  mx = fmaxf(mx, __shfl_xor(mx, 1));
  mx = fmaxf(mx, __shfl_xor(mx, 2));
  float sum = 0.0f;
#pragma unroll
  for (int i = 0; i < 16; ++i) { q[i] = expf(q[i] - mx); sum += q[i]; }
  sum += __shfl_xor(sum, 1);
  sum += __shfl_xor(sum, 2);
  float scale = 0.125f / sum;  // * e^-0.5 with e=64
#pragma unroll
  for (int i = 0; i < 16; ++i) q[i] *= scale;
  {
    uint4 pa, pb;
    pa.x = (unsigned)f2b(q[0]) | ((unsigned)f2b(q[1]) << 16);
    pa.y = (unsigned)f2b(q[2]) | ((unsigned)f2b(q[3]) << 16);
    pa.z = (unsigned)f2b(q[4]) | ((unsigned)f2b(q[5]) << 16);
    pa.w = (unsigned)f2b(q[6]) | ((unsigned)f2b(q[7]) << 16);
    pb.x = (unsigned)f2b(q[8]) | ((unsigned)f2b(q[9]) << 16);
    pb.y = (unsigned)f2b(q[10]) | ((unsigned)f2b(q[11]) << 16);
    pb.z = (unsigned)f2b(q[12]) | ((unsigned)f2b(q[13]) << 16);
    pb.w = (unsigned)f2b(q[14]) | ((unsigned)f2b(q[15]) << 16);
    int Xp = (pos & 7) << 3;
    *(uint4*)(qst + pos * 64 + ((s * 16) ^ Xp)) = pa;
    *(uint4*)(qst + pos * 64 + ((s * 16 + 8) ^ Xp)) = pb;
  }
  __syncthreads();  // cmt, qst, S ready
  float Dp = 0.0f;
#pragma unroll
  for (int i = 0; i < 16; ++i) Dp += q[i] * S[s * 16 + i];
  Dp += __shfl_xor(Dp, 1);
  Dp += __shfl_xor(Dp, 2);
  if (s == 0) dinv[pos] = 1.0f / fmaxf(Dp, 1e-3f);
  int w = t >> 6, l = t & 63;
  int X = (l & 7) << 3;
  int nl = w * 16 + (l & 15);
  floatx4 acc[4];
#pragma unroll
  for (int nf = 0; nf < 4; ++nf)
#pragma unroll
    for (int r = 0; r < 4; ++r) acc[nf][r] = 0.0f;
#pragma unroll
  for (int kc = 0; kc < 2; ++kc) {
    int doff = kc * 32 + (l >> 4) * 8;
    bf16x8 afr = *(const bf16x8*)(qst + nl * 64 + (doff ^ X));
#pragma unroll
    for (int nf = 0; nf < 4; ++nf) {
      bf16x8 bfr = *(const bf16x8*)(cmt + (nf * 16 + (l & 15)) * 64 + (doff ^ X));
      acc[nf] = __builtin_amdgcn_mfma_f32_16x16x32_bf16(afr, bfr, acc[nf], 0, 0, 0);
    }
  }
  __syncthreads();  // dinv ready
  u16* ob = att + (size_t)(batch * SEQ + u * 64) * DIM + head * DH;
#pragma unroll
  for (int r = 0; r < 4; ++r) {
    int n = w * 16 + (l >> 4) * 4 + r;
    float dv = dinv[n];
#pragma unroll
    for (int nf = 0; nf < 4; ++nf)
      ob[(size_t)n * DIM + nf * 16 + (l & 15)] = f2b(acc[nf][r] * dv);
  }
}

// ---------------- host orchestration ----------------
extern "C" void kernel_launch(void* const* d_in, const int* in_sizes, int n_in,
                              void* d_out, int out_size, void* d_ws, size_t ws_size,
                              hipStream_t stream) {
  (void)in_sizes; (void)n_in; (void)out_size; (void)ws_size;
  const void* x_in = d_in[0];
  const void* ln1_g = d_in[1];
  const void* ln1_b = d_in[2];
  const void* wq = d_in[3];
  const void* wk = d_in[4];
  const void* wv = d_in[5];
  const void* wo = d_in[6];
  const void* bo = d_in[7];
  const void* ln2_g = d_in[8];
  const void* ln2_b = d_in[9];
  const void* w1 = d_in[10];
  const void* b1 = d_in[11];
  const void* w2 = d_in[12];
  const void* b2 = d_in[13];

  char* ws = (char*)d_ws;
  float* xf = (float*)(ws);              // 16 MiB f32 residual
  u16* h = (u16*)(ws + 16777216);        // 8 MiB bf16
  u16* region = (u16*)(ws + 25165824);   // 32 MiB: qkv (24 MiB) / gb (32 MiB)
  float* Ksum = (float*)(ws + 58720256); // 256 KiB
  float* KV = (float*)(ws + 58982400);   // 16 MiB
  u16* WR = (u16*)(ws + 75759616);       // 24 MiB repacked weights
  int* dt = (int*)(ws + 100925440);      // dtype flag
  u16* qkv = region;
  u16* gb = region;

  auto WqkvR = [&](int i) { return WR + (size_t)i * LSTRIDE + 0; };
  auto WoR   = [&](int i) { return WR + (size_t)i * LSTRIDE + 786432; };
  auto W1R   = [&](int i) { return WR + (size_t)i * LSTRIDE + 1048576; };
  auto W2R   = [&](int i) { return WR + (size_t)i * LSTRIDE + 2097152; };

  k_detect<<<dim3(1), dim3(1), 0, stream>>>(ln1_g, dt);

  const int nx = ROWS * DIM;
  k_x2f<<<dim3((nx + 255) / 256), dim3(256), 0, stream>>>(x_in, xf, nx, dt);

  k_repackQ<<<dim3(16, 8, 16), dim3(256), 0, stream>>>(wq, wk, wv, wo, WR, dt);
  k_repackF1<<<dim3(16, 32, 4), dim3(256), 0, stream>>>(w1, WR, dt);
  k_repackF2<<<dim3(64, 8, 4), dim3(256), 0, stream>>>(w2, WR, dt);

  for (int i = 0; i < 4; ++i) {
    // PreNorm(attn)
    k_ln<<<dim3(ROWS), dim3(256), 0, stream>>>(xf, ln1_g, ln1_b, (long)i * DIM, h, dt);
    // fused QKV gemm: [8192,512] @ [512,1536]
    k_g8a<<<dim3(32, 6), dim3(512), 0, stream>>>(h, WqkvR(i), qkv, dt);
    k_attnA<<<dim3(1024), dim3(256), 0, stream>>>(qkv, Ksum, KV);
    k_scan2<<<dim3(1024), dim3(64), 0, stream>>>(Ksum, KV);
    k_attnC<<<dim3(1024), dim3(256), 0, stream>>>(qkv, Ksum, KV, h);  // att -> h
    // x += att @ wo + bo  (N=512, K=512)
    k_gemm3<512><<<dim3(64, 8), dim3(256), 0, stream>>>(h, WoR(i), bo, (long)i * DIM, xf, xf, dt);
    // PreNorm(FF)
    k_ln<<<dim3(ROWS), dim3(256), 0, stream>>>(xf, ln2_g, ln2_b, (long)i * DIM, h, dt);
    // FF up: [8192,512] @ [512,2048] + bias + gelu
    k_g8b<<<dim3(32, 8), dim3(512), 0, stream>>>(h, W1R(i), b1, (long)i * FFDIM, gb, dt);
    // FF down: [8192,2048] @ [2048,512] + bias + residual (N=512, K=2048)
    k_gemm3<2048><<<dim3(64, 8), dim3(256), 0, stream>>>(gb, W2R(i), b2, (long)i * DIM, xf, xf, dt);
  }

  k_store<<<dim3((nx + 255) / 256), dim3(256), 0, stream>>>(xf, d_out, nx, dt);
}